// Round 18
// baseline (64.123 us; speedup 1.0000x reference)
//
#include <hip/hip_runtime.h>
#include <math.h>

// Problem constants (B=1, H=4, N=2048, D=64, M=256)
#define NH   4
#define SEQ  2048
#define DH   64
#define NF   256
#define ROWS (NH*SEQ)                // 8192
#define DN    0.35355339059327373f   // 64^-0.25
#define DIAGC 0.0625f                // 0.5*DN*DN
#define RATIO 0.0625f                // 1/sqrt(256)
#define EPSF  1e-4f

typedef __attribute__((ext_vector_type(8))) short bf8;
typedef __attribute__((ext_vector_type(4))) short bf4;
typedef __attribute__((ext_vector_type(4))) float f4;

static __device__ __forceinline__ unsigned short f2bf(float x) {
  union { float f; unsigned u; } v; v.f = x;
  unsigned r = v.u + 0x7FFF + ((v.u >> 16) & 1);
  return (unsigned short)(r >> 16);
}
static __device__ __forceinline__ float bf2f(unsigned short b) {
  union { unsigned u; float f; } v; v.u = ((unsigned)b) << 16;
  return v.f;
}

// ---- fused projection: q-tile AND k-tile per block (shared P split) + V^T ----
// (R16 verbatim)
__global__ __launch_bounds__(256) void k_proj(const float* __restrict__ q,
    const float* __restrict__ k, const float* __restrict__ v,
    const float* __restrict__ P,
    unsigned short* __restrict__ qfb, float* __restrict__ dshd,
    float* __restrict__ bmax, unsigned short* __restrict__ vtb) {
  __shared__ float lds[64*65];
  const int b = blockIdx.x;
  if (b >= 512) {                        // ---- V transpose: 128 blocks ----
    const int cb = b - 512;
    const int h = cb >> 5, n0 = (cb & 31) * 64;
    const int tid = threadIdx.x;
    for (int i = tid; i < 4096; i += 256) {
      int n = i >> 6, e = i & 63;
      lds[n*65 + e] = v[((size_t)h*SEQ + n0 + n)*DH + e];
    }
    __syncthreads();
    for (int i = tid; i < 4096; i += 256) {
      int e = i >> 6, n = i & 63;
      vtb[((size_t)h*DH + e)*SEQ + n0 + n] = f2bf(lds[n*65 + e]);
    }
    return;
  }
  const int tile = b;                    // h*128 + t
  const int w = threadIdx.x >> 6, lane = threadIdx.x & 63;
  const int lr = lane & 15, g = lane >> 4;

  const float* xq = q + (size_t)tile*16*DH;
  const float* xk = k + (size_t)tile*16*DH;
  f4 qa = *(const f4*)(xq + lr*DH + g*8);
  f4 qb = *(const f4*)(xq + lr*DH + g*8 + 4);
  f4 qc = *(const f4*)(xq + lr*DH + 32 + g*8);
  f4 qd = *(const f4*)(xq + lr*DH + 32 + g*8 + 4);
  f4 ka = *(const f4*)(xk + lr*DH + g*8);
  f4 kb_ = *(const f4*)(xk + lr*DH + g*8 + 4);
  f4 kc = *(const f4*)(xk + lr*DH + 32 + g*8);
  f4 kd = *(const f4*)(xk + lr*DH + 32 + g*8 + 4);
  float ssq = 0.f, ssk = 0.f;
#pragma unroll
  for (int i = 0; i < 4; ++i) {
    ssq += qa[i]*qa[i] + qb[i]*qb[i] + qc[i]*qc[i] + qd[i]*qd[i];
    ssk += ka[i]*ka[i] + kb_[i]*kb_[i] + kc[i]*kc[i] + kd[i]*kd[i];
  }
  ssq += __shfl_xor(ssq, 16); ssq += __shfl_xor(ssq, 32);
  ssk += __shfl_xor(ssk, 16); ssk += __shfl_xor(ssk, 32);

  bf8 qh0, qh1, ql0, ql1, kh0, kh1, kl0, kl1;
#pragma unroll
  for (int i = 0; i < 4; ++i) {
    {
      float v0 = DN*qa[i], v1 = DN*qb[i], v2 = DN*qc[i], v3 = DN*qd[i];
      unsigned short h0 = f2bf(v0), h1 = f2bf(v1), h2 = f2bf(v2), h3 = f2bf(v3);
      qh0[i] = (short)h0; qh0[i+4] = (short)h1;
      qh1[i] = (short)h2; qh1[i+4] = (short)h3;
      ql0[i]   = (short)f2bf(v0 - bf2f(h0)); ql0[i+4] = (short)f2bf(v1 - bf2f(h1));
      ql1[i]   = (short)f2bf(v2 - bf2f(h2)); ql1[i+4] = (short)f2bf(v3 - bf2f(h3));
    }
    {
      float v0 = DN*ka[i], v1 = DN*kb_[i], v2 = DN*kc[i], v3 = DN*kd[i];
      unsigned short h0 = f2bf(v0), h1 = f2bf(v1), h2 = f2bf(v2), h3 = f2bf(v3);
      kh0[i] = (short)h0; kh0[i+4] = (short)h1;
      kh1[i] = (short)h2; kh1[i+4] = (short)h3;
      kl0[i]   = (short)f2bf(v0 - bf2f(h0)); kl0[i+4] = (short)f2bf(v1 - bf2f(h1));
      kl1[i]   = (short)f2bf(v2 - bf2f(h2)); kl1[i+4] = (short)f2bf(v3 - bf2f(h3));
    }
  }

  const int ct0 = w*4;
  f4 dshq[4], dshk[4];
#pragma unroll
  for (int cc = 0; cc < 4; ++cc) {
    const int ct = ct0 + cc;
    const float* prow = P + (ct*16 + lr)*DH + g*8;
    f4 p0 = *(const f4*)(prow);
    f4 p1 = *(const f4*)(prow + 4);
    f4 p2 = *(const f4*)(prow + 32);
    f4 p3 = *(const f4*)(prow + 36);
    bf8 bh0, bl0, bh1, bl1;
#pragma unroll
    for (int i = 0; i < 4; ++i) {
      unsigned short h0 = f2bf(p0[i]), h1 = f2bf(p1[i]);
      unsigned short h2 = f2bf(p2[i]), h3 = f2bf(p3[i]);
      bh0[i] = (short)h0; bh0[i+4] = (short)h1;
      bh1[i] = (short)h2; bh1[i+4] = (short)h3;
      bl0[i]   = (short)f2bf(p0[i] - bf2f(h0)); bl0[i+4] = (short)f2bf(p1[i] - bf2f(h1));
      bl1[i]   = (short)f2bf(p2[i] - bf2f(h2)); bl1[i+4] = (short)f2bf(p3[i] - bf2f(h3));
    }
    f4 aq = {0.f, 0.f, 0.f, 0.f};
    aq = __builtin_amdgcn_mfma_f32_16x16x32_bf16(qh0, bh0, aq, 0, 0, 0);
    aq = __builtin_amdgcn_mfma_f32_16x16x32_bf16(qh1, bh1, aq, 0, 0, 0);
    aq = __builtin_amdgcn_mfma_f32_16x16x32_bf16(qh0, bl0, aq, 0, 0, 0);
    aq = __builtin_amdgcn_mfma_f32_16x16x32_bf16(qh1, bl1, aq, 0, 0, 0);
    aq = __builtin_amdgcn_mfma_f32_16x16x32_bf16(ql0, bh0, aq, 0, 0, 0);
    aq = __builtin_amdgcn_mfma_f32_16x16x32_bf16(ql1, bh1, aq, 0, 0, 0);
    dshq[cc] = aq;
    f4 ak = {0.f, 0.f, 0.f, 0.f};
    ak = __builtin_amdgcn_mfma_f32_16x16x32_bf16(kh0, bh0, ak, 0, 0, 0);
    ak = __builtin_amdgcn_mfma_f32_16x16x32_bf16(kh1, bh1, ak, 0, 0, 0);
    ak = __builtin_amdgcn_mfma_f32_16x16x32_bf16(kh0, bl0, ak, 0, 0, 0);
    ak = __builtin_amdgcn_mfma_f32_16x16x32_bf16(kh1, bl1, ak, 0, 0, 0);
    ak = __builtin_amdgcn_mfma_f32_16x16x32_bf16(kl0, bh0, ak, 0, 0, 0);
    ak = __builtin_amdgcn_mfma_f32_16x16x32_bf16(kl1, bh1, ak, 0, 0, 0);
    dshk[cc] = ak;
  }

  f4 mrq, mrk;
#pragma unroll
  for (int r = 0; r < 4; ++r) {
    mrq[r] = fmaxf(fmaxf(dshq[0][r], dshq[1][r]), fmaxf(dshq[2][r], dshq[3][r]));
    mrk[r] = fmaxf(fmaxf(dshk[0][r], dshk[1][r]), fmaxf(dshk[2][r], dshk[3][r]));
  }
#pragma unroll
  for (int mk = 1; mk <= 8; mk <<= 1) {
#pragma unroll
    for (int r = 0; r < 4; ++r) {
      mrq[r] = fmaxf(mrq[r], __shfl_xor(mrq[r], mk));
      mrk[r] = fmaxf(mrk[r], __shfl_xor(mrk[r], mk));
    }
  }
  if (lr == 0) {
#pragma unroll
    for (int r = 0; r < 4; ++r) {
      lds[w*16 + 4*g + r]      = mrq[r];
      lds[64 + w*16 + 4*g + r] = mrk[r];
    }
  }
  __syncthreads();
  float rmq[4], rmk[4], srq[4], srk[4];
#pragma unroll
  for (int r = 0; r < 4; ++r) {
    rmq[r] = fmaxf(fmaxf(lds[0*16 + 4*g + r], lds[1*16 + 4*g + r]),
                   fmaxf(lds[2*16 + 4*g + r], lds[3*16 + 4*g + r]));
    rmk[r] = fmaxf(fmaxf(lds[64 + 0*16 + 4*g + r], lds[64 + 1*16 + 4*g + r]),
                   fmaxf(lds[64 + 2*16 + 4*g + r], lds[64 + 3*16 + 4*g + r]));
    srq[r] = __shfl(ssq, 4*g + r);
    srk[r] = __shfl(ssk, 4*g + r);
  }

  {
    unsigned short* ob = qfb + (size_t)tile*16*NF;
#pragma unroll
    for (int cc = 0; cc < 4; ++cc) {
#pragma unroll
      for (int r = 0; r < 4; ++r)
        ob[(4*g + r)*NF + (ct0 + cc)*16 + lr] =
            f2bf(RATIO*(expf(dshq[cc][r] - (srq[r]*DIAGC + rmq[r])) + EPSF));
    }
  }
  {
    float* db = dshd + (size_t)tile*16*NF;
#pragma unroll
    for (int cc = 0; cc < 4; ++cc) {
#pragma unroll
      for (int r = 0; r < 4; ++r)
        db[(4*g + r)*NF + (ct0 + cc)*16 + lr] = dshk[cc][r] - srk[r]*DIAGC;
    }
    float tmax = fmaxf(fmaxf(rmk[0], rmk[1]), fmaxf(rmk[2], rmk[3]));
    tmax = fmaxf(tmax, __shfl_xor(tmax, 16));
    tmax = fmaxf(tmax, __shfl_xor(tmax, 32));
    if (w == 0 && lane == 0) bmax[tile] = tmax;
  }
}

// ---- k_feat: gmax (512-entry) + exp -> kfb bf16 + kft (m-major) + tile sums ----
// (R16 verbatim)
__global__ __launch_bounds__(256) void k_feat2(const float* __restrict__ dshd,
    const float* __restrict__ bmax, unsigned short* __restrict__ kfb,
    unsigned short* __restrict__ kft, float* __restrict__ csum) {
  const int u = blockIdx.x, m = threadIdx.x;     // u: 0..511 = h*128 + t
  const int h = u >> 7, t = u & 127;
  __shared__ float red[256];
  red[m] = fmaxf(bmax[m], bmax[m + 256]);
  __syncthreads();
  for (int s = 128; s > 0; s >>= 1) {
    if (m < s) red[m] = fmaxf(red[m], red[m+s]);
    __syncthreads();
  }
  const float gg = red[0];
  const float* db = dshd + (size_t)u*16*NF + m;
  unsigned short* ob = kfb + (size_t)u*16*NF + m;
  float run = 0.f;
  bf8 k0, k1;
#pragma unroll
  for (int r = 0; r < 16; ++r) {
    unsigned short bv = f2bf(RATIO*(expf(db[r*NF] - gg) + EPSF));
    ob[r*NF] = bv;
    if (r < 8) k0[r] = (short)bv; else k1[r-8] = (short)bv;
    run += bf2f(bv);
  }
  csum[(size_t)u*NF + m] = run;
  unsigned short* kt = kft + ((size_t)(h*NF + m))*SEQ + t*16;
  *(bf8*)kt = k0;
  *(bf8*)(kt + 8) = k1;
}

// ---- fused state build + cumsum -> hi/lo (2-wave) + SEGMENTED csum scan ----
// blocks 0..255: unit (h,et,mt); blocks 256..271: csum scan (h,seg), csum->csumS.
__global__ __launch_bounds__(128) void k_state(
    const unsigned short* __restrict__ vtb, const unsigned short* __restrict__ kft,
    unsigned short* __restrict__ sthi, unsigned short* __restrict__ stlo,
    const float* __restrict__ csum, float* __restrict__ csumS) {
  const int bx = blockIdx.x;
  if (bx >= 256) {                       // ---- csum exclusive scan, segmented ----
    if (threadIdx.x >= 64) return;
    const int u2 = bx - 256;
    const int h = u2 >> 2, seg = u2 & 3; // 4 segments of 32 tiles per head
    const int m0 = threadIdx.x * 4;
    f4 run = {0.f, 0.f, 0.f, 0.f};
    // prefix over earlier segments, same c-order as full serial scan (bit-identical)
    for (int c = 0; c < seg*32; ++c)
      run += *(const f4*)(csum + ((size_t)(h*128 + c))*NF + m0);
    // scan own segment into csumS (csum itself stays unmodified -> no race)
    for (int c = seg*32; c < seg*32 + 32; ++c) {
      const size_t idx = ((size_t)(h*128 + c))*NF + m0;
      f4 x = *(const f4*)(csum + idx);
      *(f4*)(csumS + idx) = run;
      run += x;
    }
    return;
  }
  __shared__ f4 bridge[64];
  const int wid = threadIdx.x >> 6, lane = threadIdx.x & 63;
  const int lr = lane & 15, g = lane >> 4;
  const int h = bx >> 6, et = (bx >> 4) & 3, mt = bx & 15;

  const unsigned short* vb = vtb + ((size_t)(h*DH + et*16 + lr))*SEQ;
  const unsigned short* kb = kft + ((size_t)(h*NF + mt*16 + lr))*SEQ;

  f4 cum = {0.f, 0.f, 0.f, 0.f};
  f4 loc[8];
  const int c0 = wid*8;
#pragma unroll
  for (int cc = 0; cc < 8; ++cc) {
    const int c = c0 + cc;
    if (wid == 0) {
      const size_t base = ((size_t)((h*16 + c)*64 + et*16 + 4*g))*NF + mt*16 + lr;
#pragma unroll
      for (int r = 0; r < 4; ++r) {
        unsigned short hi = f2bf(cum[r]);
        sthi[base + (size_t)r*NF] = hi;
        stlo[base + (size_t)r*NF] = f2bf(cum[r] - bf2f(hi));
      }
    } else {
      loc[cc] = cum;
    }
#pragma unroll
    for (int ks = 0; ks < 4; ++ks) {
      const int j0 = c*128 + ks*32 + g*8;
      bf8 xv = *(const bf8*)(vb + j0);
      bf8 ym = *(const bf8*)(kb + j0);
      cum = __builtin_amdgcn_mfma_f32_16x16x32_bf16(xv, ym, cum, 0, 0, 0);
    }
  }
  if (wid == 0) bridge[lane] = cum;      // S(0..7)
  __syncthreads();
  if (wid == 1) {
    f4 s8 = bridge[lane];
#pragma unroll
    for (int cc = 0; cc < 8; ++cc) {
      const int c = 8 + cc;
      f4 val = s8 + loc[cc];
      const size_t base = ((size_t)((h*16 + c)*64 + et*16 + 4*g))*NF + mt*16 + lr;
#pragma unroll
      for (int r = 0; r < 4; ++r) {
        unsigned short hi = f2bf(val[r]);
        sthi[base + (size_t)r*NF] = hi;
        stlo[base + (size_t)r*NF] = f2bf(val[r] - bf2f(hi));
      }
    }
  }
}

// ---- chunked causal attention: 2 waves/block (wave0 inter, wave1 intra) ----
// (R16 verbatim + c==0 inter skip, bit-identical)
__global__ __launch_bounds__(128) void k_attn5(const unsigned short* __restrict__ qpb,
                                               const unsigned short* __restrict__ kfb,
                                               const unsigned short* __restrict__ vtb,
                                               const unsigned short* __restrict__ sthi,
                                               const unsigned short* __restrict__ stlo,
                                               const float* __restrict__ csum,
                                               float* __restrict__ out) {
  const int h = blockIdx.y;
  const int t = blockIdx.x;            // 0..127
  const int c = t >> 3;
  const int jc0 = c*8;
  const int nstage = (t & 7) + 1;
  const int tid = threadIdx.x;
  const int wid = tid >> 6, lane = tid & 63;
  const int lr = lane & 15, g = lane >> 4;

  __shared__ __align__(16) char smem[22528];
  // Qs [0,8192): 16 rows x 256 m bf16, XOR-swizzled
  char* Ks = smem + 8192;              // 8KB K-tile (wave1-private)
  char* Vs = smem + 16384;             // 2KB V-tile (wave1-private)
  float* MG = (float*)(smem + 18432);  // 4KB merge buffer [r4][lane][4]

  // ---- prime prologue: 128 threads x 2 m-columns ----
  {
    const int u = h*128 + t;
    const int m = tid*2;
    float run0 = csum[(size_t)u*NF + m];
    float run1 = csum[(size_t)u*NF + m + 1];
    const unsigned short* kfp = kfb + ((size_t)(h*SEQ + t*16))*NF + m;
    const unsigned short* qfp = qpb + ((size_t)(h*SEQ + t*16))*NF + m;
#pragma unroll
    for (int r = 0; r < 16; ++r) {
      unsigned kv = *(const unsigned*)(kfp + (size_t)r*NF);
      unsigned qv = *(const unsigned*)(qfp + (size_t)r*NF);
      run0 += bf2f((unsigned short)(kv & 0xffff));
      run1 += bf2f((unsigned short)(kv >> 16));
      unsigned short q0 = f2bf(bf2f((unsigned short)(qv & 0xffff)) / run0);
      unsigned short q1 = f2bf(bf2f((unsigned short)(qv >> 16)) / run1);
      const int byte = (r*512 + m*2) ^ ((r & 7) << 4);
      *(unsigned*)(smem + byte) = (unsigned)q0 | ((unsigned)q1 << 16);
    }
  }
  __syncthreads();

  // Q' A-fragments from swizzled LDS (both waves)
  bf8 qf[8];
#pragma unroll
  for (int kb = 0; kb < 8; ++kb) {
    const int byte = (lr*512 + g*16 + kb*64) ^ ((lr & 7) << 4);
    qf[kb] = *(const bf8*)(smem + byte);
  }

  f4 o0 = {0,0,0,0}, o1 = {0,0,0,0}, o2 = {0,0,0,0}, o3 = {0,0,0,0};

  if (wid == 1) {
    // ---- intra-chunk causal sweep (wave-private staging, no barriers) ----
    const char* kTile = (const char*)(kfb + (size_t)h*SEQ*NF);
    const char* vTile = (const char*)(vtb + (size_t)h*DH*SEQ);
    int kw[8];
#pragma unroll
    for (int i = 0; i < 8; ++i) {
      const int ko = i*1024 + lane*16;
      kw[i] = ko ^ (((ko >> 9) & 7) << 4);
    }
    f4 sk[8], sv0, sv1;
    {
      const char* kt = kTile + (size_t)jc0*8192;
#pragma unroll
      for (int i = 0; i < 8; ++i) sk[i] = *(const f4*)(kt + i*1024 + lane*16);
      const char* vt = vTile + (size_t)lane*4096 + (size_t)jc0*32;
      sv0 = *(const f4*)(vt);
      sv1 = *(const f4*)(vt + 16);
    }
    for (int jj = 0; jj < nstage; ++jj) {
      const int j = jc0 + jj;
#pragma unroll
      for (int i = 0; i < 8; ++i) *(f4*)(Ks + kw[i]) = sk[i];
      *(f4*)(Vs + lane*32) = sv0;
      *(f4*)(Vs + lane*32 + 16) = sv1;
      if (jj + 1 < nstage) {
        const char* kt = kTile + (size_t)(j+1)*8192;
#pragma unroll
        for (int i = 0; i < 8; ++i) sk[i] = *(const f4*)(kt + i*1024 + lane*16);
        const char* vt = vTile + (size_t)lane*4096 + (size_t)(j+1)*32;
        sv0 = *(const f4*)(vt);
        sv1 = *(const f4*)(vt + 16);
      }
      bf8 kcs[8];
#pragma unroll
      for (int kb = 0; kb < 8; ++kb) {
        int off = (lr*512 + kb*64 + g*16) ^ ((lr & 7) << 4);
        kcs[kb] = *(const bf8*)(Ks + off);
      }
      f4 st = {0,0,0,0};
#pragma unroll
      for (int kb = 0; kb < 8; ++kb)
        st = __builtin_amdgcn_mfma_f32_16x16x32_bf16(kcs[kb], qf[kb], st, 0, 0, 0);
      if (j == t) {
#pragma unroll
        for (int rr = 0; rr < 4; ++rr) if (g*4 + rr > lr) st[rr] = 0.f;
      }
      bf8 sb = { (short)f2bf(st[0]), (short)f2bf(st[1]), (short)f2bf(st[2]), (short)f2bf(st[3]),
                 (short)0, (short)0, (short)0, (short)0 };
#pragma unroll
      for (int eb = 0; eb < 4; ++eb) {
        bf4 v4 = *(const bf4*)(Vs + (eb*16 + lr)*32 + g*8);
        bf8 vf = { v4[0], v4[1], v4[2], v4[3], (short)0, (short)0, (short)0, (short)0 };
        f4 acc = (eb == 0) ? o0 : (eb == 1) ? o1 : (eb == 2) ? o2 : o3;
        acc = __builtin_amdgcn_mfma_f32_16x16x32_bf16(sb, vf, acc, 0, 0, 0);
        if (eb == 0) o0 = acc; else if (eb == 1) o1 = acc; else if (eb == 2) o2 = acc; else o3 = acc;
      }
    }
    // publish intra partials: [r4][lane] f4 (conflict-free)
    *(f4*)(MG + (0*64 + lane)*4) = o0;
    *(f4*)(MG + (1*64 + lane)*4) = o1;
    *(f4*)(MG + (2*64 + lane)*4) = o2;
    *(f4*)(MG + (3*64 + lane)*4) = o3;
  } else if (c > 0) {
    // ---- inter-chunk: O = q' x cumstate (hi/lo split); c==0 state is exactly 0 ----
    const unsigned short* SH = sthi + ((size_t)((h*16 + c)*64 + lr))*NF + g*8;
    const unsigned short* SL = stlo + ((size_t)((h*16 + c)*64 + lr))*NF + g*8;
#pragma unroll
    for (int ks = 0; ks < 8; ++ks) {
#pragma unroll
      for (int et = 0; et < 4; ++et) {
        bf8 bh = *(const bf8*)(SH + et*16*NF + ks*32);
        bf8 bl = *(const bf8*)(SL + et*16*NF + ks*32);
        f4 acc = (et == 0) ? o0 : (et == 1) ? o1 : (et == 2) ? o2 : o3;
        acc = __builtin_amdgcn_mfma_f32_16x16x32_bf16(qf[ks], bh, acc, 0, 0, 0);
        acc = __builtin_amdgcn_mfma_f32_16x16x32_bf16(qf[ks], bl, acc, 0, 0, 0);
        if (et == 0) o0 = acc; else if (et == 1) o1 = acc; else if (et == 2) o2 = acc; else o3 = acc;
      }
    }
  }
  __syncthreads();

  if (wid == 0) {
    o0 += *(const f4*)(MG + (0*64 + lane)*4);
    o1 += *(const f4*)(MG + (1*64 + lane)*4);
    o2 += *(const f4*)(MG + (2*64 + lane)*4);
    o3 += *(const f4*)(MG + (3*64 + lane)*4);
    float* ob = out + ((size_t)(h*SEQ + t*16))*DH;
#pragma unroll
    for (int rr = 0; rr < 4; ++rr) {
      ob[(size_t)(4*g + rr)*DH +  0 + lr] = o0[rr];
      ob[(size_t)(4*g + rr)*DH + 16 + lr] = o1[rr];
      ob[(size_t)(4*g + rr)*DH + 32 + lr] = o2[rr];
      ob[(size_t)(4*g + rr)*DH + 48 + lr] = o3[rr];
    }
  }
}

extern "C" void kernel_launch(void* const* d_in, const int* in_sizes, int n_in,
                              void* d_out, int out_size, void* d_ws, size_t ws_size,
                              hipStream_t stream) {
  const float* q = (const float*)d_in[0];
  const float* k = (const float*)d_in[1];
  const float* v = (const float*)d_in[2];
  const float* P = (const float*)d_in[3];
  float* out = (float*)d_out;

  char* ws = (char*)d_ws;                                    // 256 MiB available
  unsigned short* qfb  = (unsigned short*)(ws);              // 4 MB (read-only after proj)
  unsigned short* kfb  = (unsigned short*)(ws + (4u<<20));   // 4 MB
  unsigned short* vtb  = (unsigned short*)(ws + (8u<<20));   // 1 MB
  unsigned short* kft  = (unsigned short*)(ws + (12u<<20));  // 4 MB (m-major kf)
  float* dshd   = (float*)(ws + (16u<<20));                  // 8 MB
  float* bmax   = (float*)(ws + (24u<<20));                  // 2 KB (512 tiles)
  float* csum   = (float*)(ws + (25u<<20));                  // 512 KB (raw tile sums)
  float* csumS  = (float*)(ws + (26u<<20));                  // 512 KB (exclusive scan)
  unsigned short* sthi = (unsigned short*)(ws + (33u<<20));  // 2 MB
  unsigned short* stlo = (unsigned short*)(ws + (36u<<20));  // 2 MB

  k_proj  <<<640, 256, 0, stream>>>(q, k, v, P, qfb, dshd, bmax, vtb);
  k_feat2 <<<512, 256, 0, stream>>>(dshd, bmax, kfb, kft, csum);
  k_state <<<272, 128, 0, stream>>>(vtb, kft, sthi, stlo, csum, csumS);
  k_attn5 <<<dim3(128, NH), 128, 0, stream>>>(qfb, kfb, vtb, sthi, stlo, csumS, out);
}

// Round 19
// 49.990 us; speedup vs baseline: 1.2827x; 1.2827x over previous
//
#include <hip/hip_runtime.h>
#include <math.h>

// Problem constants (B=1, H=4, N=2048, D=64, M=256)
#define NH   4
#define SEQ  2048
#define DH   64
#define NF   256
#define ROWS (NH*SEQ)                // 8192
#define DN    0.35355339059327373f   // 64^-0.25
#define DIAGC 0.0625f                // 0.5*DN*DN
#define RATIO 0.0625f                // 1/sqrt(256)
#define EPSF  1e-4f

typedef __attribute__((ext_vector_type(8))) short bf8;
typedef __attribute__((ext_vector_type(4))) short bf4;
typedef __attribute__((ext_vector_type(4))) float f4;

static __device__ __forceinline__ unsigned short f2bf(float x) {
  union { float f; unsigned u; } v; v.f = x;
  unsigned r = v.u + 0x7FFF + ((v.u >> 16) & 1);
  return (unsigned short)(r >> 16);
}
static __device__ __forceinline__ float bf2f(unsigned short b) {
  union { unsigned u; float f; } v; v.u = ((unsigned)b) << 16;
  return v.f;
}

// ---- fused projection: q-tile AND k-tile per block (shared P split) + V^T ----
// blocks 0..511: tile = h*128+t (both q and k); 512..639: V transpose.
__global__ __launch_bounds__(256) void k_proj(const float* __restrict__ q,
    const float* __restrict__ k, const float* __restrict__ v,
    const float* __restrict__ P,
    unsigned short* __restrict__ qfb, float* __restrict__ dshd,
    float* __restrict__ bmax, unsigned short* __restrict__ vtb) {
  __shared__ float lds[64*65];
  const int b = blockIdx.x;
  if (b >= 512) {                        // ---- V transpose: 128 blocks ----
    const int cb = b - 512;
    const int h = cb >> 5, n0 = (cb & 31) * 64;
    const int tid = threadIdx.x;
    for (int i = tid; i < 4096; i += 256) {
      int n = i >> 6, e = i & 63;
      lds[n*65 + e] = v[((size_t)h*SEQ + n0 + n)*DH + e];
    }
    __syncthreads();
    for (int i = tid; i < 4096; i += 256) {
      int e = i >> 6, n = i & 63;
      vtb[((size_t)h*DH + e)*SEQ + n0 + n] = f2bf(lds[n*65 + e]);
    }
    return;
  }
  const int tile = b;                    // h*128 + t
  const int w = threadIdx.x >> 6, lane = threadIdx.x & 63;
  const int lr = lane & 15, g = lane >> 4;

  // ---- load + split BOTH x-tiles (q and k), row lr, cols g*8 / 32+g*8 ----
  const float* xq = q + (size_t)tile*16*DH;
  const float* xk = k + (size_t)tile*16*DH;
  f4 qa = *(const f4*)(xq + lr*DH + g*8);
  f4 qb = *(const f4*)(xq + lr*DH + g*8 + 4);
  f4 qc = *(const f4*)(xq + lr*DH + 32 + g*8);
  f4 qd = *(const f4*)(xq + lr*DH + 32 + g*8 + 4);
  f4 ka = *(const f4*)(xk + lr*DH + g*8);
  f4 kb_ = *(const f4*)(xk + lr*DH + g*8 + 4);
  f4 kc = *(const f4*)(xk + lr*DH + 32 + g*8);
  f4 kd = *(const f4*)(xk + lr*DH + 32 + g*8 + 4);
  float ssq = 0.f, ssk = 0.f;
#pragma unroll
  for (int i = 0; i < 4; ++i) {
    ssq += qa[i]*qa[i] + qb[i]*qb[i] + qc[i]*qc[i] + qd[i]*qd[i];
    ssk += ka[i]*ka[i] + kb_[i]*kb_[i] + kc[i]*kc[i] + kd[i]*kd[i];
  }
  ssq += __shfl_xor(ssq, 16); ssq += __shfl_xor(ssq, 32);
  ssk += __shfl_xor(ssk, 16); ssk += __shfl_xor(ssk, 32);

  bf8 qh0, qh1, ql0, ql1, kh0, kh1, kl0, kl1;
#pragma unroll
  for (int i = 0; i < 4; ++i) {
    {
      float v0 = DN*qa[i], v1 = DN*qb[i], v2 = DN*qc[i], v3 = DN*qd[i];
      unsigned short h0 = f2bf(v0), h1 = f2bf(v1), h2 = f2bf(v2), h3 = f2bf(v3);
      qh0[i] = (short)h0; qh0[i+4] = (short)h1;
      qh1[i] = (short)h2; qh1[i+4] = (short)h3;
      ql0[i]   = (short)f2bf(v0 - bf2f(h0)); ql0[i+4] = (short)f2bf(v1 - bf2f(h1));
      ql1[i]   = (short)f2bf(v2 - bf2f(h2)); ql1[i+4] = (short)f2bf(v3 - bf2f(h3));
    }
    {
      float v0 = DN*ka[i], v1 = DN*kb_[i], v2 = DN*kc[i], v3 = DN*kd[i];
      unsigned short h0 = f2bf(v0), h1 = f2bf(v1), h2 = f2bf(v2), h3 = f2bf(v3);
      kh0[i] = (short)h0; kh0[i+4] = (short)h1;
      kh1[i] = (short)h2; kh1[i+4] = (short)h3;
      kl0[i]   = (short)f2bf(v0 - bf2f(h0)); kl0[i+4] = (short)f2bf(v1 - bf2f(h1));
      kl1[i]   = (short)f2bf(v2 - bf2f(h2)); kl1[i+4] = (short)f2bf(v3 - bf2f(h3));
    }
  }

  const int ct0 = w*4;
  f4 dshq[4], dshk[4];
#pragma unroll
  for (int cc = 0; cc < 4; ++cc) {
    const int ct = ct0 + cc;
    const float* prow = P + (ct*16 + lr)*DH + g*8;
    f4 p0 = *(const f4*)(prow);
    f4 p1 = *(const f4*)(prow + 4);
    f4 p2 = *(const f4*)(prow + 32);
    f4 p3 = *(const f4*)(prow + 36);
    bf8 bh0, bl0, bh1, bl1;
#pragma unroll
    for (int i = 0; i < 4; ++i) {
      unsigned short h0 = f2bf(p0[i]), h1 = f2bf(p1[i]);
      unsigned short h2 = f2bf(p2[i]), h3 = f2bf(p3[i]);
      bh0[i] = (short)h0; bh0[i+4] = (short)h1;
      bh1[i] = (short)h2; bh1[i+4] = (short)h3;
      bl0[i]   = (short)f2bf(p0[i] - bf2f(h0)); bl0[i+4] = (short)f2bf(p1[i] - bf2f(h1));
      bl1[i]   = (short)f2bf(p2[i] - bf2f(h2)); bl1[i+4] = (short)f2bf(p3[i] - bf2f(h3));
    }
    f4 aq = {0.f, 0.f, 0.f, 0.f};
    aq = __builtin_amdgcn_mfma_f32_16x16x32_bf16(qh0, bh0, aq, 0, 0, 0);
    aq = __builtin_amdgcn_mfma_f32_16x16x32_bf16(qh1, bh1, aq, 0, 0, 0);
    aq = __builtin_amdgcn_mfma_f32_16x16x32_bf16(qh0, bl0, aq, 0, 0, 0);
    aq = __builtin_amdgcn_mfma_f32_16x16x32_bf16(qh1, bl1, aq, 0, 0, 0);
    aq = __builtin_amdgcn_mfma_f32_16x16x32_bf16(ql0, bh0, aq, 0, 0, 0);
    aq = __builtin_amdgcn_mfma_f32_16x16x32_bf16(ql1, bh1, aq, 0, 0, 0);
    dshq[cc] = aq;
    f4 ak = {0.f, 0.f, 0.f, 0.f};
    ak = __builtin_amdgcn_mfma_f32_16x16x32_bf16(kh0, bh0, ak, 0, 0, 0);
    ak = __builtin_amdgcn_mfma_f32_16x16x32_bf16(kh1, bh1, ak, 0, 0, 0);
    ak = __builtin_amdgcn_mfma_f32_16x16x32_bf16(kh0, bl0, ak, 0, 0, 0);
    ak = __builtin_amdgcn_mfma_f32_16x16x32_bf16(kh1, bl1, ak, 0, 0, 0);
    ak = __builtin_amdgcn_mfma_f32_16x16x32_bf16(kl0, bh0, ak, 0, 0, 0);
    ak = __builtin_amdgcn_mfma_f32_16x16x32_bf16(kl1, bh1, ak, 0, 0, 0);
    dshk[cc] = ak;
  }

  // per-row maxes (q and k), cross-lane then cross-wave via disjoint LDS
  f4 mrq, mrk;
#pragma unroll
  for (int r = 0; r < 4; ++r) {
    mrq[r] = fmaxf(fmaxf(dshq[0][r], dshq[1][r]), fmaxf(dshq[2][r], dshq[3][r]));
    mrk[r] = fmaxf(fmaxf(dshk[0][r], dshk[1][r]), fmaxf(dshk[2][r], dshk[3][r]));
  }
#pragma unroll
  for (int mk = 1; mk <= 8; mk <<= 1) {
#pragma unroll
    for (int r = 0; r < 4; ++r) {
      mrq[r] = fmaxf(mrq[r], __shfl_xor(mrq[r], mk));
      mrk[r] = fmaxf(mrk[r], __shfl_xor(mrk[r], mk));
    }
  }
  if (lr == 0) {
#pragma unroll
    for (int r = 0; r < 4; ++r) {
      lds[w*16 + 4*g + r]      = mrq[r];
      lds[64 + w*16 + 4*g + r] = mrk[r];
    }
  }
  __syncthreads();
  float rmq[4], rmk[4], srq[4], srk[4];
#pragma unroll
  for (int r = 0; r < 4; ++r) {
    rmq[r] = fmaxf(fmaxf(lds[0*16 + 4*g + r], lds[1*16 + 4*g + r]),
                   fmaxf(lds[2*16 + 4*g + r], lds[3*16 + 4*g + r]));
    rmk[r] = fmaxf(fmaxf(lds[64 + 0*16 + 4*g + r], lds[64 + 1*16 + 4*g + r]),
                   fmaxf(lds[64 + 2*16 + 4*g + r], lds[64 + 3*16 + 4*g + r]));
    srq[r] = __shfl(ssq, 4*g + r);
    srk[r] = __shfl(ssk, 4*g + r);
  }

  // ---- q epilogue: full features -> qfb ----
  {
    unsigned short* ob = qfb + (size_t)tile*16*NF;
#pragma unroll
    for (int cc = 0; cc < 4; ++cc) {
#pragma unroll
      for (int r = 0; r < 4; ++r)
        ob[(4*g + r)*NF + (ct0 + cc)*16 + lr] =
            f2bf(RATIO*(expf(dshq[cc][r] - (srq[r]*DIAGC + rmq[r])) + EPSF));
    }
  }
  // ---- k epilogue: dsh - diag -> dshd + per-tile max ----
  {
    float* db = dshd + (size_t)tile*16*NF;
#pragma unroll
    for (int cc = 0; cc < 4; ++cc) {
#pragma unroll
      for (int r = 0; r < 4; ++r)
        db[(4*g + r)*NF + (ct0 + cc)*16 + lr] = dshk[cc][r] - srk[r]*DIAGC;
    }
    float tmax = fmaxf(fmaxf(rmk[0], rmk[1]), fmaxf(rmk[2], rmk[3]));
    tmax = fmaxf(tmax, __shfl_xor(tmax, 16));
    tmax = fmaxf(tmax, __shfl_xor(tmax, 32));
    if (w == 0 && lane == 0) bmax[tile] = tmax;
  }
}

// ---- k_feat: gmax (512-entry) + exp -> kfb bf16 + kft (m-major) + tile sums ----
__global__ __launch_bounds__(256) void k_feat2(const float* __restrict__ dshd,
    const float* __restrict__ bmax, unsigned short* __restrict__ kfb,
    unsigned short* __restrict__ kft, float* __restrict__ csum) {
  const int u = blockIdx.x, m = threadIdx.x;     // u: 0..511 = h*128 + t
  const int h = u >> 7, t = u & 127;
  __shared__ float red[256];
  red[m] = fmaxf(bmax[m], bmax[m + 256]);
  __syncthreads();
  for (int s = 128; s > 0; s >>= 1) {
    if (m < s) red[m] = fmaxf(red[m], red[m+s]);
    __syncthreads();
  }
  const float gg = red[0];
  const float* db = dshd + (size_t)u*16*NF + m;
  unsigned short* ob = kfb + (size_t)u*16*NF + m;
  float run = 0.f;
  bf8 k0, k1;
#pragma unroll
  for (int r = 0; r < 16; ++r) {
    unsigned short bv = f2bf(RATIO*(expf(db[r*NF] - gg) + EPSF));
    ob[r*NF] = bv;
    if (r < 8) k0[r] = (short)bv; else k1[r-8] = (short)bv;
    run += bf2f(bv);
  }
  csum[(size_t)u*NF + m] = run;
  unsigned short* kt = kft + ((size_t)(h*NF + m))*SEQ + t*16;
  *(bf8*)kt = k0;
  *(bf8*)(kt + 8) = k1;
}

// ---- fused state build + exclusive cumsum -> hi/lo (2-wave split) + csum scan ----
__global__ __launch_bounds__(128) void k_state(
    const unsigned short* __restrict__ vtb, const unsigned short* __restrict__ kft,
    unsigned short* __restrict__ sthi, unsigned short* __restrict__ stlo,
    float* __restrict__ csum) {
  const int bx = blockIdx.x;
  if (bx >= 256) {                       // ---- csum exclusive scan (in place) ----
    if (threadIdx.x >= 64) return;
    const int h = bx - 256;
    const int m0 = threadIdx.x * 4;
    f4 run = {0.f, 0.f, 0.f, 0.f};
#pragma unroll 4
    for (int c = 0; c < 128; ++c) {
      float* p = csum + ((size_t)(h*128 + c))*NF + m0;
      f4 x = *(const f4*)p;
      *(f4*)p = run;
      run += x;
    }
    return;
  }
  __shared__ f4 bridge[64];
  const int wid = threadIdx.x >> 6, lane = threadIdx.x & 63;
  const int lr = lane & 15, g = lane >> 4;
  const int h = bx >> 6, et = (bx >> 4) & 3, mt = bx & 15;

  const unsigned short* vb = vtb + ((size_t)(h*DH + et*16 + lr))*SEQ;
  const unsigned short* kb = kft + ((size_t)(h*NF + mt*16 + lr))*SEQ;

  f4 cum = {0.f, 0.f, 0.f, 0.f};
  f4 loc[8];
  const int c0 = wid*8;
#pragma unroll
  for (int cc = 0; cc < 8; ++cc) {
    const int c = c0 + cc;
    if (wid == 0) {
      const size_t base = ((size_t)((h*16 + c)*64 + et*16 + 4*g))*NF + mt*16 + lr;
#pragma unroll
      for (int r = 0; r < 4; ++r) {
        unsigned short hi = f2bf(cum[r]);
        sthi[base + (size_t)r*NF] = hi;
        stlo[base + (size_t)r*NF] = f2bf(cum[r] - bf2f(hi));
      }
    } else {
      loc[cc] = cum;
    }
#pragma unroll
    for (int ks = 0; ks < 4; ++ks) {
      const int j0 = c*128 + ks*32 + g*8;
      bf8 xv = *(const bf8*)(vb + j0);
      bf8 ym = *(const bf8*)(kb + j0);
      cum = __builtin_amdgcn_mfma_f32_16x16x32_bf16(xv, ym, cum, 0, 0, 0);
    }
  }
  if (wid == 0) bridge[lane] = cum;      // S(0..7)
  __syncthreads();
  if (wid == 1) {
    f4 s8 = bridge[lane];
#pragma unroll
    for (int cc = 0; cc < 8; ++cc) {
      const int c = 8 + cc;
      f4 val = s8 + loc[cc];
      const size_t base = ((size_t)((h*16 + c)*64 + et*16 + 4*g))*NF + mt*16 + lr;
#pragma unroll
      for (int r = 0; r < 4; ++r) {
        unsigned short hi = f2bf(val[r]);
        sthi[base + (size_t)r*NF] = hi;
        stlo[base + (size_t)r*NF] = f2bf(val[r] - bf2f(hi));
      }
    }
  }
}

// ---- chunked causal attention: 2 waves/block (wave0 inter, wave1 intra) ----
__global__ __launch_bounds__(128) void k_attn5(const unsigned short* __restrict__ qpb,
                                               const unsigned short* __restrict__ kfb,
                                               const unsigned short* __restrict__ vtb,
                                               const unsigned short* __restrict__ sthi,
                                               const unsigned short* __restrict__ stlo,
                                               const float* __restrict__ csum,
                                               float* __restrict__ out) {
  const int h = blockIdx.y;
  const int t = blockIdx.x;            // 0..127
  const int c = t >> 3;
  const int jc0 = c*8;
  const int nstage = (t & 7) + 1;
  const int tid = threadIdx.x;
  const int wid = tid >> 6, lane = tid & 63;
  const int lr = lane & 15, g = lane >> 4;

  __shared__ __align__(16) char smem[22528];
  // Qs [0,8192): 16 rows x 256 m bf16, XOR-swizzled
  char* Ks = smem + 8192;              // 8KB K-tile (wave1-private)
  char* Vs = smem + 16384;             // 2KB V-tile (wave1-private)
  float* MG = (float*)(smem + 18432);  // 4KB merge buffer [r4][lane][4]

  // ---- prime prologue: 128 threads x 2 m-columns ----
  {
    const int u = h*128 + t;
    const int m = tid*2;
    float run0 = csum[(size_t)u*NF + m];
    float run1 = csum[(size_t)u*NF + m + 1];
    const unsigned short* kfp = kfb + ((size_t)(h*SEQ + t*16))*NF + m;
    const unsigned short* qfp = qpb + ((size_t)(h*SEQ + t*16))*NF + m;
#pragma unroll
    for (int r = 0; r < 16; ++r) {
      unsigned kv = *(const unsigned*)(kfp + (size_t)r*NF);
      unsigned qv = *(const unsigned*)(qfp + (size_t)r*NF);
      run0 += bf2f((unsigned short)(kv & 0xffff));
      run1 += bf2f((unsigned short)(kv >> 16));
      unsigned short q0 = f2bf(bf2f((unsigned short)(qv & 0xffff)) / run0);
      unsigned short q1 = f2bf(bf2f((unsigned short)(qv >> 16)) / run1);
      const int byte = (r*512 + m*2) ^ ((r & 7) << 4);
      *(unsigned*)(smem + byte) = (unsigned)q0 | ((unsigned)q1 << 16);
    }
  }
  __syncthreads();

  // Q' A-fragments from swizzled LDS (both waves)
  bf8 qf[8];
#pragma unroll
  for (int kb = 0; kb < 8; ++kb) {
    const int byte = (lr*512 + g*16 + kb*64) ^ ((lr & 7) << 4);
    qf[kb] = *(const bf8*)(smem + byte);
  }

  f4 o0 = {0,0,0,0}, o1 = {0,0,0,0}, o2 = {0,0,0,0}, o3 = {0,0,0,0};

  if (wid == 1) {
    // ---- intra-chunk causal sweep (wave-private staging, no barriers) ----
    const char* kTile = (const char*)(kfb + (size_t)h*SEQ*NF);
    const char* vTile = (const char*)(vtb + (size_t)h*DH*SEQ);
    int kw[8];
#pragma unroll
    for (int i = 0; i < 8; ++i) {
      const int ko = i*1024 + lane*16;
      kw[i] = ko ^ (((ko >> 9) & 7) << 4);
    }
    f4 sk[8], sv0, sv1;
    {
      const char* kt = kTile + (size_t)jc0*8192;
#pragma unroll
      for (int i = 0; i < 8; ++i) sk[i] = *(const f4*)(kt + i*1024 + lane*16);
      const char* vt = vTile + (size_t)lane*4096 + (size_t)jc0*32;
      sv0 = *(const f4*)(vt);
      sv1 = *(const f4*)(vt + 16);
    }
    for (int jj = 0; jj < nstage; ++jj) {
      const int j = jc0 + jj;
#pragma unroll
      for (int i = 0; i < 8; ++i) *(f4*)(Ks + kw[i]) = sk[i];
      *(f4*)(Vs + lane*32) = sv0;
      *(f4*)(Vs + lane*32 + 16) = sv1;
      if (jj + 1 < nstage) {
        const char* kt = kTile + (size_t)(j+1)*8192;
#pragma unroll
        for (int i = 0; i < 8; ++i) sk[i] = *(const f4*)(kt + i*1024 + lane*16);
        const char* vt = vTile + (size_t)lane*4096 + (size_t)(j+1)*32;
        sv0 = *(const f4*)(vt);
        sv1 = *(const f4*)(vt + 16);
      }
      bf8 kcs[8];
#pragma unroll
      for (int kb = 0; kb < 8; ++kb) {
        int off = (lr*512 + kb*64 + g*16) ^ ((lr & 7) << 4);
        kcs[kb] = *(const bf8*)(Ks + off);
      }
      f4 st = {0,0,0,0};
#pragma unroll
      for (int kb = 0; kb < 8; ++kb)
        st = __builtin_amdgcn_mfma_f32_16x16x32_bf16(kcs[kb], qf[kb], st, 0, 0, 0);
      if (j == t) {
#pragma unroll
        for (int rr = 0; rr < 4; ++rr) if (g*4 + rr > lr) st[rr] = 0.f;
      }
      bf8 sb = { (short)f2bf(st[0]), (short)f2bf(st[1]), (short)f2bf(st[2]), (short)f2bf(st[3]),
                 (short)0, (short)0, (short)0, (short)0 };
#pragma unroll
      for (int eb = 0; eb < 4; ++eb) {
        bf4 v4 = *(const bf4*)(Vs + (eb*16 + lr)*32 + g*8);
        bf8 vf = { v4[0], v4[1], v4[2], v4[3], (short)0, (short)0, (short)0, (short)0 };
        f4 acc = (eb == 0) ? o0 : (eb == 1) ? o1 : (eb == 2) ? o2 : o3;
        acc = __builtin_amdgcn_mfma_f32_16x16x32_bf16(sb, vf, acc, 0, 0, 0);
        if (eb == 0) o0 = acc; else if (eb == 1) o1 = acc; else if (eb == 2) o2 = acc; else o3 = acc;
      }
    }
    // publish intra partials: [r4][lane] f4 (conflict-free)
    *(f4*)(MG + (0*64 + lane)*4) = o0;
    *(f4*)(MG + (1*64 + lane)*4) = o1;
    *(f4*)(MG + (2*64 + lane)*4) = o2;
    *(f4*)(MG + (3*64 + lane)*4) = o3;
  } else {
    // ---- inter-chunk: O = q' x cumstate (hi/lo split) ----
    const unsigned short* SH = sthi + ((size_t)((h*16 + c)*64 + lr))*NF + g*8;
    const unsigned short* SL = stlo + ((size_t)((h*16 + c)*64 + lr))*NF + g*8;
#pragma unroll
    for (int ks = 0; ks < 8; ++ks) {
#pragma unroll
      for (int et = 0; et < 4; ++et) {
        bf8 bh = *(const bf8*)(SH + et*16*NF + ks*32);
        bf8 bl = *(const bf8*)(SL + et*16*NF + ks*32);
        f4 acc = (et == 0) ? o0 : (et == 1) ? o1 : (et == 2) ? o2 : o3;
        acc = __builtin_amdgcn_mfma_f32_16x16x32_bf16(qf[ks], bh, acc, 0, 0, 0);
        acc = __builtin_amdgcn_mfma_f32_16x16x32_bf16(qf[ks], bl, acc, 0, 0, 0);
        if (et == 0) o0 = acc; else if (et == 1) o1 = acc; else if (et == 2) o2 = acc; else o3 = acc;
      }
    }
  }
  __syncthreads();

  if (wid == 0) {
    o0 += *(const f4*)(MG + (0*64 + lane)*4);
    o1 += *(const f4*)(MG + (1*64 + lane)*4);
    o2 += *(const f4*)(MG + (2*64 + lane)*4);
    o3 += *(const f4*)(MG + (3*64 + lane)*4);
    float* ob = out + ((size_t)(h*SEQ + t*16))*DH;
#pragma unroll
    for (int rr = 0; rr < 4; ++rr) {
      ob[(size_t)(4*g + rr)*DH +  0 + lr] = o0[rr];
      ob[(size_t)(4*g + rr)*DH + 16 + lr] = o1[rr];
      ob[(size_t)(4*g + rr)*DH + 32 + lr] = o2[rr];
      ob[(size_t)(4*g + rr)*DH + 48 + lr] = o3[rr];
    }
  }
}

extern "C" void kernel_launch(void* const* d_in, const int* in_sizes, int n_in,
                              void* d_out, int out_size, void* d_ws, size_t ws_size,
                              hipStream_t stream) {
  const float* q = (const float*)d_in[0];
  const float* k = (const float*)d_in[1];
  const float* v = (const float*)d_in[2];
  const float* P = (const float*)d_in[3];
  float* out = (float*)d_out;

  char* ws = (char*)d_ws;                                    // 256 MiB available
  unsigned short* qfb  = (unsigned short*)(ws);              // 4 MB (read-only after proj)
  unsigned short* kfb  = (unsigned short*)(ws + (4u<<20));   // 4 MB
  unsigned short* vtb  = (unsigned short*)(ws + (8u<<20));   // 1 MB
  unsigned short* kft  = (unsigned short*)(ws + (12u<<20));  // 4 MB (m-major kf)
  float* dshd   = (float*)(ws + (16u<<20));                  // 8 MB
  float* bmax   = (float*)(ws + (24u<<20));                  // 2 KB (512 tiles)
  float* csum   = (float*)(ws + (25u<<20));                  // 512 KB
  unsigned short* sthi = (unsigned short*)(ws + (33u<<20));  // 2 MB
  unsigned short* stlo = (unsigned short*)(ws + (36u<<20));  // 2 MB

  k_proj  <<<640, 256, 0, stream>>>(q, k, v, P, qfb, dshd, bmax, vtb);
  k_feat2 <<<512, 256, 0, stream>>>(dshd, bmax, kfb, kft, csum);
  k_state <<<260, 128, 0, stream>>>(vtb, kft, sthi, stlo, csum);
  k_attn5 <<<dim3(128, NH), 128, 0, stream>>>(qfb, kfb, vtb, sthi, stlo, csum, out);
}

// Round 20
// 49.549 us; speedup vs baseline: 1.2941x; 1.0089x over previous
//
#include <hip/hip_runtime.h>
#include <math.h>

// Problem constants (B=1, H=4, N=2048, D=64, M=256)
#define NH   4
#define SEQ  2048
#define DH   64
#define NF   256
#define ROWS (NH*SEQ)                // 8192
#define DN    0.35355339059327373f   // 64^-0.25
#define DIAGC 0.0625f                // 0.5*DN*DN
#define RATIO 0.0625f                // 1/sqrt(256)
#define EPSF  1e-4f

typedef __attribute__((ext_vector_type(8))) short bf8;
typedef __attribute__((ext_vector_type(4))) short bf4;
typedef __attribute__((ext_vector_type(4))) float f4;

static __device__ __forceinline__ unsigned short f2bf(float x) {
  union { float f; unsigned u; } v; v.f = x;
  unsigned r = v.u + 0x7FFF + ((v.u >> 16) & 1);
  return (unsigned short)(r >> 16);
}
static __device__ __forceinline__ float bf2f(unsigned short b) {
  union { unsigned u; float f; } v; v.u = ((unsigned)b) << 16;
  return v.f;
}

// ---- fused projection: q-tile AND k-tile per block (shared P split) + V^T ----
// (R19 verbatim)
__global__ __launch_bounds__(256) void k_proj(const float* __restrict__ q,
    const float* __restrict__ k, const float* __restrict__ v,
    const float* __restrict__ P,
    unsigned short* __restrict__ qfb, float* __restrict__ dshd,
    float* __restrict__ bmax, unsigned short* __restrict__ vtb) {
  __shared__ float lds[64*65];
  const int b = blockIdx.x;
  if (b >= 512) {                        // ---- V transpose: 128 blocks ----
    const int cb = b - 512;
    const int h = cb >> 5, n0 = (cb & 31) * 64;
    const int tid = threadIdx.x;
    for (int i = tid; i < 4096; i += 256) {
      int n = i >> 6, e = i & 63;
      lds[n*65 + e] = v[((size_t)h*SEQ + n0 + n)*DH + e];
    }
    __syncthreads();
    for (int i = tid; i < 4096; i += 256) {
      int e = i >> 6, n = i & 63;
      vtb[((size_t)h*DH + e)*SEQ + n0 + n] = f2bf(lds[n*65 + e]);
    }
    return;
  }
  const int tile = b;                    // h*128 + t
  const int w = threadIdx.x >> 6, lane = threadIdx.x & 63;
  const int lr = lane & 15, g = lane >> 4;

  const float* xq = q + (size_t)tile*16*DH;
  const float* xk = k + (size_t)tile*16*DH;
  f4 qa = *(const f4*)(xq + lr*DH + g*8);
  f4 qb = *(const f4*)(xq + lr*DH + g*8 + 4);
  f4 qc = *(const f4*)(xq + lr*DH + 32 + g*8);
  f4 qd = *(const f4*)(xq + lr*DH + 32 + g*8 + 4);
  f4 ka = *(const f4*)(xk + lr*DH + g*8);
  f4 kb_ = *(const f4*)(xk + lr*DH + g*8 + 4);
  f4 kc = *(const f4*)(xk + lr*DH + 32 + g*8);
  f4 kd = *(const f4*)(xk + lr*DH + 32 + g*8 + 4);
  float ssq = 0.f, ssk = 0.f;
#pragma unroll
  for (int i = 0; i < 4; ++i) {
    ssq += qa[i]*qa[i] + qb[i]*qb[i] + qc[i]*qc[i] + qd[i]*qd[i];
    ssk += ka[i]*ka[i] + kb_[i]*kb_[i] + kc[i]*kc[i] + kd[i]*kd[i];
  }
  ssq += __shfl_xor(ssq, 16); ssq += __shfl_xor(ssq, 32);
  ssk += __shfl_xor(ssk, 16); ssk += __shfl_xor(ssk, 32);

  bf8 qh0, qh1, ql0, ql1, kh0, kh1, kl0, kl1;
#pragma unroll
  for (int i = 0; i < 4; ++i) {
    {
      float v0 = DN*qa[i], v1 = DN*qb[i], v2 = DN*qc[i], v3 = DN*qd[i];
      unsigned short h0 = f2bf(v0), h1 = f2bf(v1), h2 = f2bf(v2), h3 = f2bf(v3);
      qh0[i] = (short)h0; qh0[i+4] = (short)h1;
      qh1[i] = (short)h2; qh1[i+4] = (short)h3;
      ql0[i]   = (short)f2bf(v0 - bf2f(h0)); ql0[i+4] = (short)f2bf(v1 - bf2f(h1));
      ql1[i]   = (short)f2bf(v2 - bf2f(h2)); ql1[i+4] = (short)f2bf(v3 - bf2f(h3));
    }
    {
      float v0 = DN*ka[i], v1 = DN*kb_[i], v2 = DN*kc[i], v3 = DN*kd[i];
      unsigned short h0 = f2bf(v0), h1 = f2bf(v1), h2 = f2bf(v2), h3 = f2bf(v3);
      kh0[i] = (short)h0; kh0[i+4] = (short)h1;
      kh1[i] = (short)h2; kh1[i+4] = (short)h3;
      kl0[i]   = (short)f2bf(v0 - bf2f(h0)); kl0[i+4] = (short)f2bf(v1 - bf2f(h1));
      kl1[i]   = (short)f2bf(v2 - bf2f(h2)); kl1[i+4] = (short)f2bf(v3 - bf2f(h3));
    }
  }

  const int ct0 = w*4;
  f4 dshq[4], dshk[4];
#pragma unroll
  for (int cc = 0; cc < 4; ++cc) {
    const int ct = ct0 + cc;
    const float* prow = P + (ct*16 + lr)*DH + g*8;
    f4 p0 = *(const f4*)(prow);
    f4 p1 = *(const f4*)(prow + 4);
    f4 p2 = *(const f4*)(prow + 32);
    f4 p3 = *(const f4*)(prow + 36);
    bf8 bh0, bl0, bh1, bl1;
#pragma unroll
    for (int i = 0; i < 4; ++i) {
      unsigned short h0 = f2bf(p0[i]), h1 = f2bf(p1[i]);
      unsigned short h2 = f2bf(p2[i]), h3 = f2bf(p3[i]);
      bh0[i] = (short)h0; bh0[i+4] = (short)h1;
      bh1[i] = (short)h2; bh1[i+4] = (short)h3;
      bl0[i]   = (short)f2bf(p0[i] - bf2f(h0)); bl0[i+4] = (short)f2bf(p1[i] - bf2f(h1));
      bl1[i]   = (short)f2bf(p2[i] - bf2f(h2)); bl1[i+4] = (short)f2bf(p3[i] - bf2f(h3));
    }
    f4 aq = {0.f, 0.f, 0.f, 0.f};
    aq = __builtin_amdgcn_mfma_f32_16x16x32_bf16(qh0, bh0, aq, 0, 0, 0);
    aq = __builtin_amdgcn_mfma_f32_16x16x32_bf16(qh1, bh1, aq, 0, 0, 0);
    aq = __builtin_amdgcn_mfma_f32_16x16x32_bf16(qh0, bl0, aq, 0, 0, 0);
    aq = __builtin_amdgcn_mfma_f32_16x16x32_bf16(qh1, bl1, aq, 0, 0, 0);
    aq = __builtin_amdgcn_mfma_f32_16x16x32_bf16(ql0, bh0, aq, 0, 0, 0);
    aq = __builtin_amdgcn_mfma_f32_16x16x32_bf16(ql1, bh1, aq, 0, 0, 0);
    dshq[cc] = aq;
    f4 ak = {0.f, 0.f, 0.f, 0.f};
    ak = __builtin_amdgcn_mfma_f32_16x16x32_bf16(kh0, bh0, ak, 0, 0, 0);
    ak = __builtin_amdgcn_mfma_f32_16x16x32_bf16(kh1, bh1, ak, 0, 0, 0);
    ak = __builtin_amdgcn_mfma_f32_16x16x32_bf16(kh0, bl0, ak, 0, 0, 0);
    ak = __builtin_amdgcn_mfma_f32_16x16x32_bf16(kh1, bl1, ak, 0, 0, 0);
    ak = __builtin_amdgcn_mfma_f32_16x16x32_bf16(kl0, bh0, ak, 0, 0, 0);
    ak = __builtin_amdgcn_mfma_f32_16x16x32_bf16(kl1, bh1, ak, 0, 0, 0);
    dshk[cc] = ak;
  }

  f4 mrq, mrk;
#pragma unroll
  for (int r = 0; r < 4; ++r) {
    mrq[r] = fmaxf(fmaxf(dshq[0][r], dshq[1][r]), fmaxf(dshq[2][r], dshq[3][r]));
    mrk[r] = fmaxf(fmaxf(dshk[0][r], dshk[1][r]), fmaxf(dshk[2][r], dshk[3][r]));
  }
#pragma unroll
  for (int mk = 1; mk <= 8; mk <<= 1) {
#pragma unroll
    for (int r = 0; r < 4; ++r) {
      mrq[r] = fmaxf(mrq[r], __shfl_xor(mrq[r], mk));
      mrk[r] = fmaxf(mrk[r], __shfl_xor(mrk[r], mk));
    }
  }
  if (lr == 0) {
#pragma unroll
    for (int r = 0; r < 4; ++r) {
      lds[w*16 + 4*g + r]      = mrq[r];
      lds[64 + w*16 + 4*g + r] = mrk[r];
    }
  }
  __syncthreads();
  float rmq[4], rmk[4], srq[4], srk[4];
#pragma unroll
  for (int r = 0; r < 4; ++r) {
    rmq[r] = fmaxf(fmaxf(lds[0*16 + 4*g + r], lds[1*16 + 4*g + r]),
                   fmaxf(lds[2*16 + 4*g + r], lds[3*16 + 4*g + r]));
    rmk[r] = fmaxf(fmaxf(lds[64 + 0*16 + 4*g + r], lds[64 + 1*16 + 4*g + r]),
                   fmaxf(lds[64 + 2*16 + 4*g + r], lds[64 + 3*16 + 4*g + r]));
    srq[r] = __shfl(ssq, 4*g + r);
    srk[r] = __shfl(ssk, 4*g + r);
  }

  {
    unsigned short* ob = qfb + (size_t)tile*16*NF;
#pragma unroll
    for (int cc = 0; cc < 4; ++cc) {
#pragma unroll
      for (int r = 0; r < 4; ++r)
        ob[(4*g + r)*NF + (ct0 + cc)*16 + lr] =
            f2bf(RATIO*(expf(dshq[cc][r] - (srq[r]*DIAGC + rmq[r])) + EPSF));
    }
  }
  {
    float* db = dshd + (size_t)tile*16*NF;
#pragma unroll
    for (int cc = 0; cc < 4; ++cc) {
#pragma unroll
      for (int r = 0; r < 4; ++r)
        db[(4*g + r)*NF + (ct0 + cc)*16 + lr] = dshk[cc][r] - srk[r]*DIAGC;
    }
    float tmax = fmaxf(fmaxf(rmk[0], rmk[1]), fmaxf(rmk[2], rmk[3]));
    tmax = fmaxf(tmax, __shfl_xor(tmax, 16));
    tmax = fmaxf(tmax, __shfl_xor(tmax, 32));
    if (w == 0 && lane == 0) bmax[tile] = tmax;
  }
}

// ---- k_feat: gmax (512-entry) + exp -> kfb bf16 + kft (m-major) + tile sums ----
// (R19 verbatim)
__global__ __launch_bounds__(256) void k_feat2(const float* __restrict__ dshd,
    const float* __restrict__ bmax, unsigned short* __restrict__ kfb,
    unsigned short* __restrict__ kft, float* __restrict__ csum) {
  const int u = blockIdx.x, m = threadIdx.x;     // u: 0..511 = h*128 + t
  const int h = u >> 7, t = u & 127;
  __shared__ float red[256];
  red[m] = fmaxf(bmax[m], bmax[m + 256]);
  __syncthreads();
  for (int s = 128; s > 0; s >>= 1) {
    if (m < s) red[m] = fmaxf(red[m], red[m+s]);
    __syncthreads();
  }
  const float gg = red[0];
  const float* db = dshd + (size_t)u*16*NF + m;
  unsigned short* ob = kfb + (size_t)u*16*NF + m;
  float run = 0.f;
  bf8 k0, k1;
#pragma unroll
  for (int r = 0; r < 16; ++r) {
    unsigned short bv = f2bf(RATIO*(expf(db[r*NF] - gg) + EPSF));
    ob[r*NF] = bv;
    if (r < 8) k0[r] = (short)bv; else k1[r-8] = (short)bv;
    run += bf2f(bv);
  }
  csum[(size_t)u*NF + m] = run;
  unsigned short* kt = kft + ((size_t)(h*NF + m))*SEQ + t*16;
  *(bf8*)kt = k0;
  *(bf8*)(kt + 8) = k1;
}

// ---- fused state build + exclusive cumsum -> hi/lo (2-wave split) + csum scan ----
// (R19 verbatim)
__global__ __launch_bounds__(128) void k_state(
    const unsigned short* __restrict__ vtb, const unsigned short* __restrict__ kft,
    unsigned short* __restrict__ sthi, unsigned short* __restrict__ stlo,
    float* __restrict__ csum) {
  const int bx = blockIdx.x;
  if (bx >= 256) {                       // ---- csum exclusive scan (in place) ----
    if (threadIdx.x >= 64) return;
    const int h = bx - 256;
    const int m0 = threadIdx.x * 4;
    f4 run = {0.f, 0.f, 0.f, 0.f};
#pragma unroll 4
    for (int c = 0; c < 128; ++c) {
      float* p = csum + ((size_t)(h*128 + c))*NF + m0;
      f4 x = *(const f4*)p;
      *(f4*)p = run;
      run += x;
    }
    return;
  }
  __shared__ f4 bridge[64];
  const int wid = threadIdx.x >> 6, lane = threadIdx.x & 63;
  const int lr = lane & 15, g = lane >> 4;
  const int h = bx >> 6, et = (bx >> 4) & 3, mt = bx & 15;

  const unsigned short* vb = vtb + ((size_t)(h*DH + et*16 + lr))*SEQ;
  const unsigned short* kb = kft + ((size_t)(h*NF + mt*16 + lr))*SEQ;

  f4 cum = {0.f, 0.f, 0.f, 0.f};
  f4 loc[8];
  const int c0 = wid*8;
#pragma unroll
  for (int cc = 0; cc < 8; ++cc) {
    const int c = c0 + cc;
    if (wid == 0) {
      const size_t base = ((size_t)((h*16 + c)*64 + et*16 + 4*g))*NF + mt*16 + lr;
#pragma unroll
      for (int r = 0; r < 4; ++r) {
        unsigned short hi = f2bf(cum[r]);
        sthi[base + (size_t)r*NF] = hi;
        stlo[base + (size_t)r*NF] = f2bf(cum[r] - bf2f(hi));
      }
    } else {
      loc[cc] = cum;
    }
#pragma unroll
    for (int ks = 0; ks < 4; ++ks) {
      const int j0 = c*128 + ks*32 + g*8;
      bf8 xv = *(const bf8*)(vb + j0);
      bf8 ym = *(const bf8*)(kb + j0);
      cum = __builtin_amdgcn_mfma_f32_16x16x32_bf16(xv, ym, cum, 0, 0, 0);
    }
  }
  if (wid == 0) bridge[lane] = cum;      // S(0..7)
  __syncthreads();
  if (wid == 1) {
    f4 s8 = bridge[lane];
#pragma unroll
    for (int cc = 0; cc < 8; ++cc) {
      const int c = 8 + cc;
      f4 val = s8 + loc[cc];
      const size_t base = ((size_t)((h*16 + c)*64 + et*16 + 4*g))*NF + mt*16 + lr;
#pragma unroll
      for (int r = 0; r < 4; ++r) {
        unsigned short hi = f2bf(val[r]);
        sthi[base + (size_t)r*NF] = hi;
        stlo[base + (size_t)r*NF] = f2bf(val[r] - bf2f(hi));
      }
    }
  }
}

// ---- chunked causal attention: 2 waves/block; wave1 double-buffered read-first ----
__global__ __launch_bounds__(128) void k_attn7(const unsigned short* __restrict__ qpb,
                                               const unsigned short* __restrict__ kfb,
                                               const unsigned short* __restrict__ vtb,
                                               const unsigned short* __restrict__ sthi,
                                               const unsigned short* __restrict__ stlo,
                                               const float* __restrict__ csum,
                                               float* __restrict__ out) {
  const int h = blockIdx.y;
  const int t = blockIdx.x;            // 0..127
  const int c = t >> 3;
  const int jc0 = c*8;
  const int nstage = (t & 7) + 1;
  const int tid = threadIdx.x;
  const int wid = tid >> 6, lane = tid & 63;
  const int lr = lane & 15, g = lane >> 4;

  __shared__ __align__(16) char smem[32768];
  // Qs [0,8192): 16 rows x 256 m bf16, XOR-swizzled
  // Ks0 [8192,16384), Ks1 [16384,24576): double-buffered K tiles (XOR-swizzled)
  // Vs0 [24576,26624), Vs1 [26624,28672): double-buffered V tiles
  // MG  [28672,32768): merge buffer
  float* MG = (float*)(smem + 28672);

  // ---- prime prologue: 128 threads x 2 m-columns ----
  {
    const int u = h*128 + t;
    const int m = tid*2;
    float run0 = csum[(size_t)u*NF + m];
    float run1 = csum[(size_t)u*NF + m + 1];
    const unsigned short* kfp = kfb + ((size_t)(h*SEQ + t*16))*NF + m;
    const unsigned short* qfp = qpb + ((size_t)(h*SEQ + t*16))*NF + m;
#pragma unroll
    for (int r = 0; r < 16; ++r) {
      unsigned kv = *(const unsigned*)(kfp + (size_t)r*NF);
      unsigned qv = *(const unsigned*)(qfp + (size_t)r*NF);
      run0 += bf2f((unsigned short)(kv & 0xffff));
      run1 += bf2f((unsigned short)(kv >> 16));
      unsigned short q0 = f2bf(bf2f((unsigned short)(qv & 0xffff)) / run0);
      unsigned short q1 = f2bf(bf2f((unsigned short)(qv >> 16)) / run1);
      const int byte = (r*512 + m*2) ^ ((r & 7) << 4);
      *(unsigned*)(smem + byte) = (unsigned)q0 | ((unsigned)q1 << 16);
    }
  }
  __syncthreads();

  // Q' A-fragments from swizzled LDS (both waves)
  bf8 qf[8];
#pragma unroll
  for (int kb = 0; kb < 8; ++kb) {
    const int byte = (lr*512 + g*16 + kb*64) ^ ((lr & 7) << 4);
    qf[kb] = *(const bf8*)(smem + byte);
  }

  f4 o0 = {0,0,0,0}, o1 = {0,0,0,0}, o2 = {0,0,0,0}, o3 = {0,0,0,0};

  if (wid == 1) {
    // ---- intra sweep: double-buffered LDS, read-first ordering, no barriers ----
    const char* kTile = (const char*)(kfb + (size_t)h*SEQ*NF);
    const char* vTile = (const char*)(vtb + (size_t)h*DH*SEQ);
    int kw[8];
#pragma unroll
    for (int i = 0; i < 8; ++i) {
      const int ko = i*1024 + lane*16;
      kw[i] = ko ^ (((ko >> 9) & 7) << 4);
    }
    int kro[8];
#pragma unroll
    for (int kb = 0; kb < 8; ++kb)
      kro[kb] = (lr*512 + kb*64 + g*16) ^ ((lr & 7) << 4);

    f4 sk[8], sv0, sv1;
    {  // prologue: load tile j0, write to buf0
      const char* kt = kTile + (size_t)jc0*8192;
#pragma unroll
      for (int i = 0; i < 8; ++i) sk[i] = *(const f4*)(kt + i*1024 + lane*16);
      const char* vt = vTile + (size_t)lane*4096 + (size_t)jc0*32;
      sv0 = *(const f4*)(vt);
      sv1 = *(const f4*)(vt + 16);
      char* Ks0 = smem + 8192;
      char* Vs0 = smem + 24576;
#pragma unroll
      for (int i = 0; i < 8; ++i) *(f4*)(Ks0 + kw[i]) = sk[i];
      *(f4*)(Vs0 + lane*32) = sv0;
      *(f4*)(Vs0 + lane*32 + 16) = sv1;
      if (nstage > 1) {  // issue loads for j0+1
        const char* kt1 = kTile + (size_t)(jc0 + 1)*8192;
#pragma unroll
        for (int i = 0; i < 8; ++i) sk[i] = *(const f4*)(kt1 + i*1024 + lane*16);
        const char* vt1 = vTile + (size_t)lane*4096 + (size_t)(jc0 + 1)*32;
        sv0 = *(const f4*)(vt1);
        sv1 = *(const f4*)(vt1 + 16);
      }
    }

    int cur = 0;
    for (int jj = 0; jj < nstage; ++jj) {
      const int j = jc0 + jj;
      char* Ks = smem + 8192 + cur*8192;
      char* Vs = smem + 24576 + cur*2048;
      // 1) read current tile's fragments FIRST (K + all V up-front)
      bf8 kcs[8];
#pragma unroll
      for (int kb = 0; kb < 8; ++kb) kcs[kb] = *(const bf8*)(Ks + kro[kb]);
      bf4 v4s[4];
#pragma unroll
      for (int eb = 0; eb < 4; ++eb)
        v4s[eb] = *(const bf4*)(Vs + (eb*16 + lr)*32 + g*8);
      // 2) write NEXT tile into the other buffer (overlaps with compute below)
      if (jj + 1 < nstage) {
        char* Ksn = smem + 8192 + (cur^1)*8192;
        char* Vsn = smem + 24576 + (cur^1)*2048;
#pragma unroll
        for (int i = 0; i < 8; ++i) *(f4*)(Ksn + kw[i]) = sk[i];
        *(f4*)(Vsn + lane*32) = sv0;
        *(f4*)(Vsn + lane*32 + 16) = sv1;
        if (jj + 2 < nstage) {  // 3) issue loads for tile j+2
          const char* kt = kTile + (size_t)(j + 2)*8192;
#pragma unroll
          for (int i = 0; i < 8; ++i) sk[i] = *(const f4*)(kt + i*1024 + lane*16);
          const char* vt = vTile + (size_t)lane*4096 + (size_t)(j + 2)*32;
          sv0 = *(const f4*)(vt);
          sv1 = *(const f4*)(vt + 16);
        }
      }
      // 4) compute (MFMAs depend only on the reads in step 1)
      f4 st = {0,0,0,0};
#pragma unroll
      for (int kb = 0; kb < 8; ++kb)
        st = __builtin_amdgcn_mfma_f32_16x16x32_bf16(kcs[kb], qf[kb], st, 0, 0, 0);
      if (j == t) {
#pragma unroll
        for (int rr = 0; rr < 4; ++rr) if (g*4 + rr > lr) st[rr] = 0.f;
      }
      bf8 sb = { (short)f2bf(st[0]), (short)f2bf(st[1]), (short)f2bf(st[2]), (short)f2bf(st[3]),
                 (short)0, (short)0, (short)0, (short)0 };
#pragma unroll
      for (int eb = 0; eb < 4; ++eb) {
        bf8 vf = { v4s[eb][0], v4s[eb][1], v4s[eb][2], v4s[eb][3],
                   (short)0, (short)0, (short)0, (short)0 };
        f4 acc = (eb == 0) ? o0 : (eb == 1) ? o1 : (eb == 2) ? o2 : o3;
        acc = __builtin_amdgcn_mfma_f32_16x16x32_bf16(sb, vf, acc, 0, 0, 0);
        if (eb == 0) o0 = acc; else if (eb == 1) o1 = acc; else if (eb == 2) o2 = acc; else o3 = acc;
      }
      cur ^= 1;
    }
    // publish intra partials: [r4][lane] f4 (conflict-free)
    *(f4*)(MG + (0*64 + lane)*4) = o0;
    *(f4*)(MG + (1*64 + lane)*4) = o1;
    *(f4*)(MG + (2*64 + lane)*4) = o2;
    *(f4*)(MG + (3*64 + lane)*4) = o3;
  } else {
    // ---- inter-chunk: O = q' x cumstate (hi/lo split) ----
    const unsigned short* SH = sthi + ((size_t)((h*16 + c)*64 + lr))*NF + g*8;
    const unsigned short* SL = stlo + ((size_t)((h*16 + c)*64 + lr))*NF + g*8;
#pragma unroll
    for (int ks = 0; ks < 8; ++ks) {
#pragma unroll
      for (int et = 0; et < 4; ++et) {
        bf8 bh = *(const bf8*)(SH + et*16*NF + ks*32);
        bf8 bl = *(const bf8*)(SL + et*16*NF + ks*32);
        f4 acc = (et == 0) ? o0 : (et == 1) ? o1 : (et == 2) ? o2 : o3;
        acc = __builtin_amdgcn_mfma_f32_16x16x32_bf16(qf[ks], bh, acc, 0, 0, 0);
        acc = __builtin_amdgcn_mfma_f32_16x16x32_bf16(qf[ks], bl, acc, 0, 0, 0);
        if (et == 0) o0 = acc; else if (et == 1) o1 = acc; else if (et == 2) o2 = acc; else o3 = acc;
      }
    }
  }
  __syncthreads();

  if (wid == 0) {
    o0 += *(const f4*)(MG + (0*64 + lane)*4);
    o1 += *(const f4*)(MG + (1*64 + lane)*4);
    o2 += *(const f4*)(MG + (2*64 + lane)*4);
    o3 += *(const f4*)(MG + (3*64 + lane)*4);
    float* ob = out + ((size_t)(h*SEQ + t*16))*DH;
#pragma unroll
    for (int rr = 0; rr < 4; ++rr) {
      ob[(size_t)(4*g + rr)*DH +  0 + lr] = o0[rr];
      ob[(size_t)(4*g + rr)*DH + 16 + lr] = o1[rr];
      ob[(size_t)(4*g + rr)*DH + 32 + lr] = o2[rr];
      ob[(size_t)(4*g + rr)*DH + 48 + lr] = o3[rr];
    }
  }
}

extern "C" void kernel_launch(void* const* d_in, const int* in_sizes, int n_in,
                              void* d_out, int out_size, void* d_ws, size_t ws_size,
                              hipStream_t stream) {
  const float* q = (const float*)d_in[0];
  const float* k = (const float*)d_in[1];
  const float* v = (const float*)d_in[2];
  const float* P = (const float*)d_in[3];
  float* out = (float*)d_out;

  char* ws = (char*)d_ws;                                    // 256 MiB available
  unsigned short* qfb  = (unsigned short*)(ws);              // 4 MB (read-only after proj)
  unsigned short* kfb  = (unsigned short*)(ws + (4u<<20));   // 4 MB
  unsigned short* vtb  = (unsigned short*)(ws + (8u<<20));   // 1 MB
  unsigned short* kft  = (unsigned short*)(ws + (12u<<20));  // 4 MB (m-major kf)
  float* dshd   = (float*)(ws + (16u<<20));                  // 8 MB
  float* bmax   = (float*)(ws + (24u<<20));                  // 2 KB (512 tiles)
  float* csum   = (float*)(ws + (25u<<20));                  // 512 KB
  unsigned short* sthi = (unsigned short*)(ws + (33u<<20));  // 2 MB
  unsigned short* stlo = (unsigned short*)(ws + (36u<<20));  // 2 MB

  k_proj  <<<640, 256, 0, stream>>>(q, k, v, P, qfb, dshd, bmax, vtb);
  k_feat2 <<<512, 256, 0, stream>>>(dshd, bmax, kfb, kft, csum);
  k_state <<<260, 128, 0, stream>>>(vtb, kft, sthi, stlo, csum);
  k_attn7 <<<dim3(128, NH), 128, 0, stream>>>(qfb, kfb, vtb, sthi, stlo, csum, out);
}